// Round 1
// baseline (327.668 us; speedup 1.0000x reference)
//
#include <hip/hip_runtime.h>
#include <stdint.h>

#define M_DIM 4096
#define N_DIM 4096
#define K_DIM 4096

typedef __bf16 bf16x8 __attribute__((ext_vector_type(8)));
typedef float  f32x4  __attribute__((ext_vector_type(4)));

// ---------- RNE float -> bf16 bits (finite inputs only) ----------
__device__ __forceinline__ unsigned short f2bf(float f) {
    unsigned u = __float_as_uint(f);
    u += 0x7FFFu + ((u >> 16) & 1u);   // round-to-nearest-even
    return (unsigned short)(u >> 16);
}

// ---------------- Kernel 1: max |W| -> uint bits ----------------
__global__ void maxabs_kernel(const float* __restrict__ w,
                              unsigned int* __restrict__ out_bits, int n4) {
    int tid = blockIdx.x * blockDim.x + threadIdx.x;
    int stride = gridDim.x * blockDim.x;
    const float4* w4 = (const float4*)w;
    float m = 0.0f;
    for (int i = tid; i < n4; i += stride) {
        float4 v = w4[i];
        m = fmaxf(m, fmaxf(fmaxf(fabsf(v.x), fabsf(v.y)),
                           fmaxf(fabsf(v.z), fabsf(v.w))));
    }
    for (int off = 32; off > 0; off >>= 1)
        m = fmaxf(m, __shfl_xor(m, off));
    if ((threadIdx.x & 63) == 0)
        atomicMax(out_bits, __float_as_uint(m));   // |w| >= 0: uint order == float order
}

// ------- Kernel 2: quantize W -> bf16(w_deq); convert x -> bf16 -------
__global__ void quant_convert_kernel(const float* __restrict__ w,
                                     const float* __restrict__ x,
                                     const unsigned int* __restrict__ max_bits,
                                     unsigned short* __restrict__ wb,
                                     unsigned short* __restrict__ xb,
                                     int n4_each) {
    const float maxv  = __uint_as_float(*max_bits);
    const float scale = 127.0f / maxv;           // same fp32 ops as reference
    int tid = blockIdx.x * blockDim.x + threadIdx.x;
    int stride = gridDim.x * blockDim.x;
    const float4* w4 = (const float4*)w;
    const float4* x4 = (const float4*)x;
    ushort4* wb4 = (ushort4*)wb;
    ushort4* xb4 = (ushort4*)xb;
    const int total = 2 * n4_each;
    for (int i = tid; i < total; i += stride) {
        if (i < n4_each) {
            float4 v = w4[i];
            ushort4 o;
            {
                float q = fminf(fmaxf(truncf(v.x * scale), -127.0f), 127.0f);
                o.x = f2bf(q / scale);
            }
            {
                float q = fminf(fmaxf(truncf(v.y * scale), -127.0f), 127.0f);
                o.y = f2bf(q / scale);
            }
            {
                float q = fminf(fmaxf(truncf(v.z * scale), -127.0f), 127.0f);
                o.z = f2bf(q / scale);
            }
            {
                float q = fminf(fmaxf(truncf(v.w * scale), -127.0f), 127.0f);
                o.w = f2bf(q / scale);
            }
            wb4[i] = o;
        } else {
            int j = i - n4_each;
            float4 v = x4[j];
            ushort4 o;
            o.x = f2bf(v.x); o.y = f2bf(v.y); o.z = f2bf(v.z); o.w = f2bf(v.w);
            xb4[j] = o;
        }
    }
}

// ---------------- Kernel 3: bf16 GEMM C = A * B^T + bias ----------------
// A: [M][K] bf16 (x), B: [N][K] bf16 (w_deq), C: [M][N] fp32.
// m97 structure: 128x128 tile, BK=64, 4 waves (2x2), each wave 64x64 = 4x4
// frags of mfma_f32_16x16x32_bf16; global_load_lds width-16 staging.
#define BM 128
#define BN 128
#define BK 64

__global__ __launch_bounds__(256) void gemm_bt_bias(
    const unsigned short* __restrict__ A,
    const unsigned short* __restrict__ B,
    const float* __restrict__ bias,
    float* __restrict__ C)
{
    __shared__ __align__(16) unsigned short sA[BM * BK];  // [128][64] row-major
    __shared__ __align__(16) unsigned short sB[BN * BK];  // [128][64] row-major

    const int bid = blockIdx.x;
    const int bm = bid / (N_DIM / BN);
    const int bn = bid % (N_DIM / BN);

    const int t    = threadIdx.x;
    const int wave = t >> 6;       // 0..3
    const int lane = t & 63;
    const int wm   = wave >> 1;    // 0..1 : 64-row half
    const int wn   = wave & 1;     // 0..1 : 64-col half

    f32x4 acc[4][4] = {};

    // Staging: thread t handles 16B chunk t within each 4KB (32-row) group.
    const int r = t >> 3;          // row within 32-row group
    const int c = t & 7;           // 16B chunk within 128B row
    const unsigned short* a_src = A + ((size_t)(bm * BM + r)) * K_DIM + c * 8;
    const unsigned short* b_src = B + ((size_t)(bn * BN + r)) * K_DIM + c * 8;

    char* sAc = (char*)sA;
    char* sBc = (char*)sB;

    for (int kt = 0; kt < K_DIM; kt += BK) {
        // ---- stage A tile (128x64 bf16 = 16KB) : 4 insts x 4KB ----
        #pragma unroll
        for (int i = 0; i < 4; ++i) {
            __builtin_amdgcn_global_load_lds(
                (const __attribute__((address_space(1))) void*)(a_src + i * 32 * K_DIM + kt),
                (__attribute__((address_space(3))) void*)(sAc + i * 4096 + wave * 1024),
                16, 0, 0);
        }
        #pragma unroll
        for (int i = 0; i < 4; ++i) {
            __builtin_amdgcn_global_load_lds(
                (const __attribute__((address_space(1))) void*)(b_src + i * 32 * K_DIM + kt),
                (__attribute__((address_space(3))) void*)(sBc + i * 4096 + wave * 1024),
                16, 0, 0);
        }
        __syncthreads();   // compiler emits vmcnt(0) drain before s_barrier

        // ---- compute: 2 k-steps of 32, 16 MFMA each ----
        #pragma unroll
        for (int kk = 0; kk < 2; ++kk) {
            const int kbyte = kk * 64 + (lane >> 4) * 16;  // (k0 + 8*(lane>>4)) * 2B
            bf16x8 af[4], bfr[4];
            #pragma unroll
            for (int mi = 0; mi < 4; ++mi)
                af[mi] = *(const bf16x8*)(sAc + (wm * 64 + mi * 16 + (lane & 15)) * 128 + kbyte);
            #pragma unroll
            for (int ni = 0; ni < 4; ++ni)
                bfr[ni] = *(const bf16x8*)(sBc + (wn * 64 + ni * 16 + (lane & 15)) * 128 + kbyte);
            #pragma unroll
            for (int mi = 0; mi < 4; ++mi)
                #pragma unroll
                for (int ni = 0; ni < 4; ++ni)
                    acc[mi][ni] = __builtin_amdgcn_mfma_f32_16x16x32_bf16(
                        af[mi], bfr[ni], acc[mi][ni], 0, 0, 0);
        }
        __syncthreads();
    }

    // ---- epilogue: C[row][col] = acc + bias[col] ----
    // D layout (m89-verified): col = lane&15, row = (lane>>4)*4 + reg
    const int col0 = bn * BN + wn * 64 + (lane & 15);
    const int row0 = bm * BM + wm * 64 + (lane >> 4) * 4;
    #pragma unroll
    for (int ni = 0; ni < 4; ++ni) {
        const float bv = bias[col0 + ni * 16];
        #pragma unroll
        for (int mi = 0; mi < 4; ++mi) {
            #pragma unroll
            for (int rg = 0; rg < 4; ++rg) {
                C[(size_t)(row0 + mi * 16 + rg) * N_DIM + col0 + ni * 16] =
                    acc[mi][ni][rg] + bv;
            }
        }
    }
}

extern "C" void kernel_launch(void* const* d_in, const int* in_sizes, int n_in,
                              void* d_out, int out_size, void* d_ws, size_t ws_size,
                              hipStream_t stream) {
    const float* x    = (const float*)d_in[0];   // [4096, 4096]
    const float* w    = (const float*)d_in[1];   // [4096, 4096]
    const float* bias = (const float*)d_in[2];   // [4096]
    float* out = (float*)d_out;

    unsigned int*  maxbits = (unsigned int*)d_ws;
    unsigned short* xb = (unsigned short*)((char*)d_ws + 256);
    unsigned short* wb = (unsigned short*)((char*)d_ws + 256 + (size_t)M_DIM * K_DIM * 2);

    hipMemsetAsync(d_ws, 0, 4, stream);

    const int n4 = (N_DIM * K_DIM) / 4;
    maxabs_kernel<<<2048, 256, 0, stream>>>(w, maxbits, n4);
    quant_convert_kernel<<<2048, 256, 0, stream>>>(w, x, maxbits, wb, xb, n4);

    const int grid = (M_DIM / BM) * (N_DIM / BN);  // 1024
    gemm_bt_bias<<<grid, 256, 0, stream>>>(xb, wb, bias, out);
}

// Round 2
// 257.250 us; speedup vs baseline: 1.2737x; 1.2737x over previous
//
#include <hip/hip_runtime.h>
#include <stdint.h>

#define M_DIM 4096
#define N_DIM 4096
#define K_DIM 4096

typedef __bf16 bf16x8 __attribute__((ext_vector_type(8)));
typedef float  f32x4  __attribute__((ext_vector_type(4)));

// ---------- RNE float -> bf16 bits (finite inputs only) ----------
__device__ __forceinline__ unsigned short f2bf(float f) {
    unsigned u = __float_as_uint(f);
    u += 0x7FFFu + ((u >> 16) & 1u);   // round-to-nearest-even
    return (unsigned short)(u >> 16);
}

// ---- Kernel 1: max|W| (atomic per wave) + convert x -> bf16 (scale-independent) ----
__global__ void maxabs_convx_kernel(const float* __restrict__ w,
                                    const float* __restrict__ x,
                                    unsigned int* __restrict__ out_bits,
                                    unsigned short* __restrict__ xb, int n4) {
    int tid = blockIdx.x * blockDim.x + threadIdx.x;
    int stride = gridDim.x * blockDim.x;
    const float4* w4 = (const float4*)w;
    const float4* x4 = (const float4*)x;
    ushort4* xb4 = (ushort4*)xb;
    float m = 0.0f;
    for (int i = tid; i < n4; i += stride) {
        float4 v = w4[i];
        m = fmaxf(m, fmaxf(fmaxf(fabsf(v.x), fabsf(v.y)),
                           fmaxf(fabsf(v.z), fabsf(v.w))));
        float4 u = x4[i];
        ushort4 o;
        o.x = f2bf(u.x); o.y = f2bf(u.y); o.z = f2bf(u.z); o.w = f2bf(u.w);
        xb4[i] = o;
    }
    for (int off = 32; off > 0; off >>= 1)
        m = fmaxf(m, __shfl_xor(m, off));
    if ((threadIdx.x & 63) == 0)
        atomicMax(out_bits, __float_as_uint(m));   // |w|>=0: uint order == float order
}

// ---- Kernel 2: quantize W -> bf16(w_deq) (mul by inv scale, no fp32 div) ----
__global__ void quant_w_kernel(const float* __restrict__ w,
                               const unsigned int* __restrict__ max_bits,
                               unsigned short* __restrict__ wb, int n4) {
    const float maxv  = __uint_as_float(*max_bits);
    const float scale = 127.0f / maxv;
    const float qinv  = maxv * (1.0f / 127.0f);   // == 1/scale to 1 ulp
    int tid = blockIdx.x * blockDim.x + threadIdx.x;
    int stride = gridDim.x * blockDim.x;
    const float4* w4 = (const float4*)w;
    ushort4* wb4 = (ushort4*)wb;
    for (int i = tid; i < n4; i += stride) {
        float4 v = w4[i];
        ushort4 o;
        o.x = f2bf(fminf(fmaxf(truncf(v.x * scale), -127.0f), 127.0f) * qinv);
        o.y = f2bf(fminf(fmaxf(truncf(v.y * scale), -127.0f), 127.0f) * qinv);
        o.z = f2bf(fminf(fmaxf(truncf(v.z * scale), -127.0f), 127.0f) * qinv);
        o.w = f2bf(fminf(fmaxf(truncf(v.w * scale), -127.0f), 127.0f) * qinv);
        wb4[i] = o;
    }
}

// ---------------- Kernel 3: 256x256 8-phase bf16 GEMM, C = A * B^T + bias ----------------
// A: [M][K] bf16 (x), B: [N][K] bf16 (w_deq), C: [M][N] fp32.
// 512 thr = 8 waves (2M x 4N); per-wave C = 128x64 (rows wm*64+{0..63} in each 128-half,
// cols wn*32+{0..31} in each 128-half); 4 quadrants (h,g) gray-ordered per K-tile,
// 16 MFMA each. LDS: 2 dbuf x (A,B) x 2 halves x [128][64] bf16 = 128 KiB.
// Swizzle: byte ^= (row&7)<<4 (both-sides: pre-swizzled global src + swizzled ds_read).
#define BM 256
#define BN 256
#define BK 64

#define BAR()   do { asm volatile("" ::: "memory"); __builtin_amdgcn_s_barrier(); asm volatile("" ::: "memory"); } while(0)
#define LGKM0() do { asm volatile("s_waitcnt lgkmcnt(0)" ::: "memory"); __builtin_amdgcn_sched_barrier(0); } while(0)
#define VM6()   do { asm volatile("s_waitcnt vmcnt(6)"   ::: "memory"); __builtin_amdgcn_sched_barrier(0); } while(0)

__global__ __launch_bounds__(512, 2) void gemm_bt_bias(
    const unsigned short* __restrict__ A,
    const unsigned short* __restrict__ B,
    const float* __restrict__ bias,
    float* __restrict__ C)
{
    __shared__ __align__(16) unsigned short sA[2][BM][BK];  // 64 KiB: [buf][row(2 halves)][k]
    __shared__ __align__(16) unsigned short sB[2][BN][BK];  // 64 KiB

    // XCD-aware swizzle: nwg=256, divisible by 8 -> simple bijective remap
    int bid = (blockIdx.x & 7) * 32 + (blockIdx.x >> 3);
    const int bm = bid >> 4;    // 0..15
    const int bn = bid & 15;

    const int t    = threadIdx.x;
    const int wave = t >> 6;
    const int lane = t & 63;
    const int wm   = wave >> 2;     // 0..1
    const int wn   = wave & 3;      // 0..3

    char* sAb = (char*)sA;
    char* sBb = (char*)sB;

    f32x4 acc[2][2][4][2] = {};     // [h][g][mi][ni]

    // Staging invariants: thread t owns linear LDS slot t*16 (+ i*8192) in each half-tile.
    // Linear slot o -> row = o>>7, chunk = (o>>4)&7; source column pre-swizzled by ^(row&7).
    const int srow = t >> 3;                         // 0..63 (row within 64-row i-block)
    const int cch  = ((t & 7) ^ ((t >> 3) & 7));     // swizzled 16B chunk 0..7
    const int wave_lds = wave * 1024;

    const unsigned short* Abase = A + (size_t)(bm * BM) * K_DIM;
    const unsigned short* Bbase = B + (size_t)(bn * BN) * K_DIM;

    // stage one half-tile (128 rows x 64 k) of A or B: 2 x global_load_lds(16B)/thread
#define STAGE(MATB, LDSB, H, KT, BUF) do {                                              \
        const unsigned short* _s = MATB + (size_t)((H)*128 + srow) * K_DIM              \
                                        + (KT)*64 + cch*8;                              \
        char* _d = LDSB + (BUF)*32768 + (H)*16384 + wave_lds;                           \
        __builtin_amdgcn_global_load_lds(                                               \
            (const __attribute__((address_space(1))) void*)_s,                          \
            (__attribute__((address_space(3))) void*)_d, 16, 0, 0);                     \
        __builtin_amdgcn_global_load_lds(                                               \
            (const __attribute__((address_space(1))) void*)(_s + (size_t)64 * K_DIM),   \
            (__attribute__((address_space(3))) void*)(_d + 8192), 16, 0, 0);            \
    } while(0)

    // load A-fragments for half H from buf BUF: 8 x ds_read_b128 (swizzled)
#define LDA(H, BUF, AF) do {                                                            \
        _Pragma("unroll") for (int mi = 0; mi < 4; ++mi)                                \
        _Pragma("unroll") for (int kk = 0; kk < 2; ++kk) {                              \
            int _row = (H)*128 + wm*64 + mi*16 + (lane & 15);                           \
            int _off = (BUF)*32768 + _row*128 + kk*64 + ((lane >> 4) << 4);             \
            _off ^= (_row & 7) << 4;                                                    \
            AF[mi][kk] = *(const bf16x8*)(sAb + _off);                                  \
        }                                                                               \
    } while(0)

    // load B-fragments for col-half G from buf BUF: 4 x ds_read_b128 (swizzled)
#define LDB(G, BUF, BF) do {                                                            \
        _Pragma("unroll") for (int ni = 0; ni < 2; ++ni)                                \
        _Pragma("unroll") for (int kk = 0; kk < 2; ++kk) {                              \
            int _row = (G)*128 + wn*32 + ni*16 + (lane & 15);                           \
            int _off = (BUF)*32768 + _row*128 + kk*64 + ((lane >> 4) << 4);             \
            _off ^= (_row & 7) << 4;                                                    \
            BF[ni][kk] = *(const bf16x8*)(sBb + _off);                                  \
        }                                                                               \
    } while(0)

    // one C-quadrant x K=64: 16 MFMA, setprio-wrapped
#define MMA(H, G, AF, BF) do {                                                          \
        __builtin_amdgcn_s_setprio(1);                                                  \
        _Pragma("unroll") for (int mi = 0; mi < 4; ++mi)                                \
        _Pragma("unroll") for (int ni = 0; ni < 2; ++ni) {                              \
            acc[H][G][mi][ni] = __builtin_amdgcn_mfma_f32_16x16x32_bf16(                \
                AF[mi][0], BF[ni][0], acc[H][G][mi][ni], 0, 0, 0);                      \
            acc[H][G][mi][ni] = __builtin_amdgcn_mfma_f32_16x16x32_bf16(                \
                AF[mi][1], BF[ni][1], acc[H][G][mi][ni], 0, 0, 0);                      \
        }                                                                               \
        __builtin_amdgcn_s_setprio(0);                                                  \
    } while(0)

    // Prologue: tile0 fully + tile1 minus A1 (7 half-tile units); wait until only the
    // newest 3 units (= 6 loads) are outstanding -> tile 0 fully landed.
    STAGE(Abase, sAb, 0, 0, 0);
    STAGE(Abase, sAb, 1, 0, 0);
    STAGE(Bbase, sBb, 0, 0, 0);
    STAGE(Bbase, sBb, 1, 0, 0);
    STAGE(Abase, sAb, 0, 1, 1);
    STAGE(Bbase, sBb, 0, 1, 1);
    STAGE(Bbase, sBb, 1, 1, 1);
    VM6();
    BAR();

    bf16x8 af[4][2], bf0[2][2], bf1[2][2];

    for (int it = 0; it < 32; ++it) {
        // ---- K-tile 2it in buf0: quadrants (0,0) (0,1) (1,1) (1,0) ----
        // P1
        LDA(0, 0, af); LDB(0, 0, bf0);
        STAGE(Abase, sAb, 1, (2*it + 1) & 63, 1);   // A1(T+1) into buf1 (slot freed prev P8)
        BAR(); LGKM0();
        MMA(0, 0, af, bf0);
        BAR();
        // P2
        LDB(1, 0, bf1);
        STAGE(Abase, sAb, 0, (2*it + 2) & 63, 0);   // A0(T+2) (A0(T) consumed in P1)
        BAR(); LGKM0();
        MMA(0, 1, af, bf1);
        BAR();
        // P3
        LDA(1, 0, af);
        STAGE(Bbase, sBb, 0, (2*it + 2) & 63, 0);   // B0(T+2) (B0(T) retained in regs)
        BAR(); LGKM0();
        MMA(1, 1, af, bf1);
        BAR();
        // P4 (no ds_reads; b0 retained from P1)
        STAGE(Bbase, sBb, 1, (2*it + 2) & 63, 0);   // B1(T+2) (B1(T) consumed P2/P3)
        VM6();                                       // oldest beyond 3 units landed
        BAR(); LGKM0();
        MMA(1, 0, af, bf0);
        BAR();

        // ---- K-tile 2it+1 in buf1 ----
        // P5
        LDA(0, 1, af); LDB(0, 1, bf0);
        STAGE(Abase, sAb, 1, (2*it + 2) & 63, 0);   // A1(T+2) (A1(T) consumed P3/P4)
        BAR(); LGKM0();
        MMA(0, 0, af, bf0);
        BAR();
        // P6
        LDB(1, 1, bf1);
        STAGE(Abase, sAb, 0, (2*it + 3) & 63, 1);   // A0(T+3)
        BAR(); LGKM0();
        MMA(0, 1, af, bf1);
        BAR();
        // P7
        LDA(1, 1, af);
        STAGE(Bbase, sBb, 0, (2*it + 3) & 63, 1);   // B0(T+3)
        BAR(); LGKM0();
        MMA(1, 1, af, bf1);
        BAR();
        // P8
        STAGE(Bbase, sBb, 1, (2*it + 3) & 63, 1);   // B1(T+3)
        VM6();
        BAR(); LGKM0();
        MMA(1, 0, af, bf0);
        BAR();
    }

    // ---- epilogue: C[row][col] = acc + bias[col] ----
    // D layout (m89): col = lane&15 (B-frag row = n), row = (lane>>4)*4 + reg (A-frag row = m)
    #pragma unroll
    for (int h = 0; h < 2; ++h)
    #pragma unroll
    for (int g = 0; g < 2; ++g)
    #pragma unroll
    for (int mi = 0; mi < 4; ++mi)
    #pragma unroll
    for (int ni = 0; ni < 2; ++ni) {
        const int grow0 = bm * BM + h * 128 + wm * 64 + mi * 16 + (lane >> 4) * 4;
        const int gcol  = bn * BN + g * 128 + wn * 32 + ni * 16 + (lane & 15);
        const float bv = bias[gcol];
        #pragma unroll
        for (int rg = 0; rg < 4; ++rg)
            C[(size_t)(grow0 + rg) * N_DIM + gcol] = acc[h][g][mi][ni][rg] + bv;
    }

#undef STAGE
#undef LDA
#undef LDB
#undef MMA
}

extern "C" void kernel_launch(void* const* d_in, const int* in_sizes, int n_in,
                              void* d_out, int out_size, void* d_ws, size_t ws_size,
                              hipStream_t stream) {
    const float* x    = (const float*)d_in[0];   // [4096, 4096]
    const float* w    = (const float*)d_in[1];   // [4096, 4096]
    const float* bias = (const float*)d_in[2];   // [4096]
    float* out = (float*)d_out;

    unsigned int*   maxbits = (unsigned int*)d_ws;
    unsigned short* xb = (unsigned short*)((char*)d_ws + 256);
    unsigned short* wb = (unsigned short*)((char*)d_ws + 256 + (size_t)M_DIM * K_DIM * 2);

    hipMemsetAsync(d_ws, 0, 4, stream);

    const int n4 = (N_DIM * K_DIM) / 4;
    maxabs_convx_kernel<<<2048, 256, 0, stream>>>(w, x, maxbits, xb, n4);
    quant_w_kernel<<<2048, 256, 0, stream>>>(w, maxbits, wb, n4);

    const int grid = (M_DIM / BM) * (N_DIM / BN);  // 256
    gemm_bt_bias<<<grid, 512, 0, stream>>>(xb, wb, bias, out);
}

// Round 3
// 182.773 us; speedup vs baseline: 1.7928x; 1.4075x over previous
//
#include <hip/hip_runtime.h>
#include <stdint.h>

#define M_DIM 4096
#define N_DIM 4096
#define K_DIM 4096

typedef __bf16 bf16x8 __attribute__((ext_vector_type(8)));
typedef float  f32x4  __attribute__((ext_vector_type(4)));

// ---------- RNE float -> bf16 bits (finite inputs only) ----------
__device__ __forceinline__ unsigned short f2bf(float f) {
    unsigned u = __float_as_uint(f);
    u += 0x7FFFu + ((u >> 16) & 1u);   // round-to-nearest-even
    return (unsigned short)(u >> 16);
}

// ---- Kernel 1: max|W| -> one atomic per BLOCK (LDS-reduced) ----
__global__ void maxabs_kernel(const float* __restrict__ w,
                              unsigned int* __restrict__ out_bits, int n4) {
    __shared__ float sred[4];
    int tid = blockIdx.x * blockDim.x + threadIdx.x;
    int stride = gridDim.x * blockDim.x;
    const float4* w4 = (const float4*)w;
    float m = 0.0f;
    for (int i = tid; i < n4; i += stride) {
        float4 v = w4[i];
        m = fmaxf(m, fmaxf(fmaxf(fabsf(v.x), fabsf(v.y)),
                           fmaxf(fabsf(v.z), fabsf(v.w))));
    }
    for (int off = 32; off > 0; off >>= 1)
        m = fmaxf(m, __shfl_xor(m, off));
    if ((threadIdx.x & 63) == 0) sred[threadIdx.x >> 6] = m;
    __syncthreads();
    if (threadIdx.x == 0) {
        m = fmaxf(fmaxf(sred[0], sred[1]), fmaxf(sred[2], sred[3]));
        atomicMax(out_bits, __float_as_uint(m));  // |w|>=0: uint order == float order
    }
}

// ---- Kernel 2: quantize W -> bf16(w_deq) AND convert x -> bf16 ----
__global__ void quant_convx_kernel(const float* __restrict__ w,
                                   const float* __restrict__ x,
                                   const unsigned int* __restrict__ max_bits,
                                   unsigned short* __restrict__ wb,
                                   unsigned short* __restrict__ xb, int n4) {
    const float maxv  = __uint_as_float(*max_bits);
    const float scale = 127.0f / maxv;
    const float qinv  = maxv * (1.0f / 127.0f);   // == 1/scale to 1 ulp
    int tid = blockIdx.x * blockDim.x + threadIdx.x;
    int stride = gridDim.x * blockDim.x;
    const float4* w4 = (const float4*)w;
    const float4* x4 = (const float4*)x;
    ushort4* wb4 = (ushort4*)wb;
    ushort4* xb4 = (ushort4*)xb;
    for (int i = tid; i < n4; i += stride) {
        float4 v = w4[i];
        ushort4 o;
        o.x = f2bf(fminf(fmaxf(truncf(v.x * scale), -127.0f), 127.0f) * qinv);
        o.y = f2bf(fminf(fmaxf(truncf(v.y * scale), -127.0f), 127.0f) * qinv);
        o.z = f2bf(fminf(fmaxf(truncf(v.z * scale), -127.0f), 127.0f) * qinv);
        o.w = f2bf(fminf(fmaxf(truncf(v.w * scale), -127.0f), 127.0f) * qinv);
        wb4[i] = o;
        float4 u = x4[i];
        ushort4 p;
        p.x = f2bf(u.x); p.y = f2bf(u.y); p.z = f2bf(u.z); p.w = f2bf(u.w);
        xb4[i] = p;
    }
}

// ---------------- Kernel 3: 256x256 8-phase bf16 GEMM, C = A * B^T + bias ----------------
// A: [M][K] bf16 (x), B: [N][K] bf16 (w_deq), C: [M][N] fp32.
// 512 thr = 8 waves (2M x 4N); per-wave C = 128x64; 4 quadrants (h,g) gray-ordered
// per K-tile, 16 MFMA each. LDS: 2 dbuf x (A,B) x 2 halves x [128][64] bf16 = 128 KiB.
// Swizzle: byte ^= (row&7)<<4 (both-sides: pre-swizzled global src + swizzled ds_read).
// Sync (m201-faithful): plain s_barrier (NO memory clobber -> compiler may overlap
// next-phase ds_reads with MFMA); NO explicit lgkmcnt (compiler emits counted waits);
// counted vmcnt(6) once per K-tile + sched_barrier(0) fence to pin staged-read order.
#define BM 256
#define BN 256
#define BK 64

#define BAR()   __builtin_amdgcn_s_barrier()
#define FENCE() __builtin_amdgcn_sched_barrier(0)
#define VM6()   do { asm volatile("s_waitcnt vmcnt(6)"); FENCE(); } while(0)

__global__ __launch_bounds__(512, 2) void gemm_bt_bias(
    const unsigned short* __restrict__ A,
    const unsigned short* __restrict__ B,
    const float* __restrict__ bias,
    float* __restrict__ C)
{
    __shared__ __align__(16) unsigned short sA[2][BM][BK];  // 64 KiB
    __shared__ __align__(16) unsigned short sB[2][BN][BK];  // 64 KiB

    // XCD-aware swizzle: nwg=256, divisible by 8 -> bijective remap
    int bid = (blockIdx.x & 7) * 32 + (blockIdx.x >> 3);
    const int bm = bid >> 4;
    const int bn = bid & 15;

    const int t    = threadIdx.x;
    const int wave = t >> 6;
    const int lane = t & 63;
    const int wm   = wave >> 2;     // 0..1
    const int wn   = wave & 3;      // 0..3

    char* sAb = (char*)sA;
    char* sBb = (char*)sB;

    f32x4 acc[2][2][4][2] = {};     // [h][g][mi][ni]

    // Staging: thread t owns linear LDS slot t*16 (+8192 for 2nd 64-row block).
    const int srow = t >> 3;                         // row within 64-row block
    const int cch  = ((t & 7) ^ ((t >> 3) & 7));     // pre-swizzled 16B chunk
    const int wave_lds = wave * 1024;

    const unsigned short* Abase = A + (size_t)(bm * BM) * K_DIM;
    const unsigned short* Bbase = B + (size_t)(bn * BN) * K_DIM;

#define STAGE(MATB, LDSB, H, KT, BUF) do {                                              \
        const unsigned short* _s = MATB + (size_t)((H)*128 + srow) * K_DIM              \
                                        + (KT)*64 + cch*8;                              \
        char* _d = LDSB + (BUF)*32768 + (H)*16384 + wave_lds;                           \
        __builtin_amdgcn_global_load_lds(                                               \
            (const __attribute__((address_space(1))) void*)_s,                          \
            (__attribute__((address_space(3))) void*)_d, 16, 0, 0);                     \
        __builtin_amdgcn_global_load_lds(                                               \
            (const __attribute__((address_space(1))) void*)(_s + (size_t)64 * K_DIM),   \
            (__attribute__((address_space(3))) void*)(_d + 8192), 16, 0, 0);            \
    } while(0)

#define LDA(H, BUF, AF) do {                                                            \
        _Pragma("unroll") for (int mi = 0; mi < 4; ++mi)                                \
        _Pragma("unroll") for (int kk = 0; kk < 2; ++kk) {                              \
            int _row = (H)*128 + wm*64 + mi*16 + (lane & 15);                           \
            int _off = (BUF)*32768 + _row*128 + kk*64 + ((lane >> 4) << 4);             \
            _off ^= (_row & 7) << 4;                                                    \
            AF[mi][kk] = *(const bf16x8*)(sAb + _off);                                  \
        }                                                                               \
    } while(0)

#define LDB(G, BUF, BF) do {                                                            \
        _Pragma("unroll") for (int ni = 0; ni < 2; ++ni)                                \
        _Pragma("unroll") for (int kk = 0; kk < 2; ++kk) {                              \
            int _row = (G)*128 + wn*32 + ni*16 + (lane & 15);                           \
            int _off = (BUF)*32768 + _row*128 + kk*64 + ((lane >> 4) << 4);             \
            _off ^= (_row & 7) << 4;                                                    \
            BF[ni][kk] = *(const bf16x8*)(sBb + _off);                                  \
        }                                                                               \
    } while(0)

#define MMA(H, G, AF, BF) do {                                                          \
        __builtin_amdgcn_s_setprio(1);                                                  \
        _Pragma("unroll") for (int mi = 0; mi < 4; ++mi)                                \
        _Pragma("unroll") for (int ni = 0; ni < 2; ++ni) {                              \
            acc[H][G][mi][ni] = __builtin_amdgcn_mfma_f32_16x16x32_bf16(                \
                AF[mi][0], BF[ni][0], acc[H][G][mi][ni], 0, 0, 0);                      \
            acc[H][G][mi][ni] = __builtin_amdgcn_mfma_f32_16x16x32_bf16(                \
                AF[mi][1], BF[ni][1], acc[H][G][mi][ni], 0, 0, 0);                      \
        }                                                                               \
        __builtin_amdgcn_s_setprio(0);                                                  \
    } while(0)

    // Prologue: tile0 fully + tile1 minus A1 (7 half-tile units = 14 loads);
    // drain to 6 outstanding -> tile0 fully landed.
    STAGE(Abase, sAb, 0, 0, 0);
    STAGE(Abase, sAb, 1, 0, 0);
    STAGE(Bbase, sBb, 0, 0, 0);
    STAGE(Bbase, sBb, 1, 0, 0);
    STAGE(Abase, sAb, 0, 1, 1);
    STAGE(Bbase, sBb, 0, 1, 1);
    STAGE(Bbase, sBb, 1, 1, 1);
    VM6();
    BAR();

    bf16x8 af[4][2], bf0[2][2], bf1[2][2];

    for (int it = 0; it < 32; ++it) {
        // ---- K-tile 2it in buf0: quadrants (0,0) (0,1) (1,1) (1,0) ----
        FENCE();   // post-VM6/BAR boundary: staged-buf reads must not hoist above
        // P1
        LDA(0, 0, af); LDB(0, 0, bf0);
        STAGE(Abase, sAb, 1, (2*it + 1) & 63, 1);
        BAR();
        MMA(0, 0, af, bf0);
        BAR();
        // P2
        LDB(1, 0, bf1);
        STAGE(Abase, sAb, 0, (2*it + 2) & 63, 0);
        BAR();
        MMA(0, 1, af, bf1);
        BAR();
        // P3
        LDA(1, 0, af);
        STAGE(Bbase, sBb, 0, (2*it + 2) & 63, 0);
        BAR();
        MMA(1, 1, af, bf1);
        BAR();
        // P4
        STAGE(Bbase, sBb, 1, (2*it + 2) & 63, 0);
        VM6();
        BAR();
        MMA(1, 0, af, bf0);
        BAR();

        // ---- K-tile 2it+1 in buf1 ----
        FENCE();
        // P5
        LDA(0, 1, af); LDB(0, 1, bf0);
        STAGE(Abase, sAb, 1, (2*it + 2) & 63, 0);
        BAR();
        MMA(0, 0, af, bf0);
        BAR();
        // P6
        LDB(1, 1, bf1);
        STAGE(Abase, sAb, 0, (2*it + 3) & 63, 1);
        BAR();
        MMA(0, 1, af, bf1);
        BAR();
        // P7
        LDA(1, 1, af);
        STAGE(Bbase, sBb, 0, (2*it + 3) & 63, 1);
        BAR();
        MMA(1, 1, af, bf1);
        BAR();
        // P8
        STAGE(Bbase, sBb, 1, (2*it + 3) & 63, 1);
        VM6();
        BAR();
        MMA(1, 0, af, bf0);
        BAR();
    }

    asm volatile("s_waitcnt vmcnt(0)");   // drain tail stages before endpgm

    // ---- epilogue: C[row][col] = acc + bias[col] ----
    // D layout (m89): col = lane&15, row = (lane>>4)*4 + reg
    #pragma unroll
    for (int h = 0; h < 2; ++h)
    #pragma unroll
    for (int g = 0; g < 2; ++g)
    #pragma unroll
    for (int mi = 0; mi < 4; ++mi)
    #pragma unroll
    for (int ni = 0; ni < 2; ++ni) {
        const int grow0 = bm * BM + h * 128 + wm * 64 + mi * 16 + (lane >> 4) * 4;
        const int gcol  = bn * BN + g * 128 + wn * 32 + ni * 16 + (lane & 15);
        const float bv = bias[gcol];
        #pragma unroll
        for (int rg = 0; rg < 4; ++rg)
            C[(size_t)(grow0 + rg) * N_DIM + gcol] = acc[h][g][mi][ni][rg] + bv;
    }

#undef STAGE
#undef LDA
#undef LDB
#undef MMA
}

extern "C" void kernel_launch(void* const* d_in, const int* in_sizes, int n_in,
                              void* d_out, int out_size, void* d_ws, size_t ws_size,
                              hipStream_t stream) {
    const float* x    = (const float*)d_in[0];   // [4096, 4096]
    const float* w    = (const float*)d_in[1];   // [4096, 4096]
    const float* bias = (const float*)d_in[2];   // [4096]
    float* out = (float*)d_out;

    unsigned int*   maxbits = (unsigned int*)d_ws;
    unsigned short* xb = (unsigned short*)((char*)d_ws + 256);
    unsigned short* wb = (unsigned short*)((char*)d_ws + 256 + (size_t)M_DIM * K_DIM * 2);

    hipMemsetAsync(d_ws, 0, 4, stream);

    const int n4 = (N_DIM * K_DIM) / 4;
    maxabs_kernel<<<512, 256, 0, stream>>>(w, maxbits, n4);
    quant_convx_kernel<<<2048, 256, 0, stream>>>(w, x, maxbits, wb, xb, n4);

    const int grid = (M_DIM / BM) * (N_DIM / BN);  // 256
    gemm_bt_bias<<<grid, 512, 0, stream>>>(xb, wb, bias, out);
}

// Round 4
// 134.879 us; speedup vs baseline: 2.4294x; 1.3551x over previous
//
#include <hip/hip_runtime.h>
#include <stdint.h>

#define M_DIM 4096
#define N_DIM 4096
#define K_DIM 4096

typedef int   i32x4 __attribute__((ext_vector_type(4)));

// ---- Kernel 1: wmax = max|W|, xmax = max|x| -> uint bits (one atomic pair per block) ----
__global__ void maxabs2_kernel(const float* __restrict__ w,
                               const float* __restrict__ x,
                               unsigned int* __restrict__ out_bits, int n4) {
    __shared__ float swm[4], sxm[4];
    int tid = blockIdx.x * blockDim.x + threadIdx.x;
    int stride = gridDim.x * blockDim.x;
    const float4* w4 = (const float4*)w;
    const float4* x4 = (const float4*)x;
    float mw = 0.f, mx = 0.f;
    for (int i = tid; i < n4; i += stride) {
        float4 a = w4[i];
        mw = fmaxf(mw, fmaxf(fmaxf(fabsf(a.x), fabsf(a.y)), fmaxf(fabsf(a.z), fabsf(a.w))));
        float4 b = x4[i];
        mx = fmaxf(mx, fmaxf(fmaxf(fabsf(b.x), fabsf(b.y)), fmaxf(fabsf(b.z), fabsf(b.w))));
    }
    for (int off = 32; off > 0; off >>= 1) {
        mw = fmaxf(mw, __shfl_xor(mw, off));
        mx = fmaxf(mx, __shfl_xor(mx, off));
    }
    if ((threadIdx.x & 63) == 0) { swm[threadIdx.x >> 6] = mw; sxm[threadIdx.x >> 6] = mx; }
    __syncthreads();
    if (threadIdx.x == 0) {
        mw = fmaxf(fmaxf(swm[0], swm[1]), fmaxf(swm[2], swm[3]));
        mx = fmaxf(fmaxf(sxm[0], sxm[1]), fmaxf(sxm[2], sxm[3]));
        atomicMax(&out_bits[0], __float_as_uint(mw));   // values >= 0: uint order == float order
        atomicMax(&out_bits[1], __float_as_uint(mx));
    }
}

// ---- Kernel 2: W -> int8 (trunc, exact reference semantics); x -> int8 (RNE) ----
__global__ void quant_kernel(const float* __restrict__ w,
                             const float* __restrict__ x,
                             const unsigned int* __restrict__ mb,
                             int* __restrict__ wq4,   // packed 4x int8
                             int* __restrict__ xq4, int n4) {
    const float wscale = 127.0f / __uint_as_float(mb[0]);
    const float xscale = 127.0f / __uint_as_float(mb[1]);
    int tid = blockIdx.x * blockDim.x + threadIdx.x;
    int stride = gridDim.x * blockDim.x;
    const float4* w4 = (const float4*)w;
    const float4* x4 = (const float4*)x;
    for (int i = tid; i < n4; i += stride) {
        float4 a = w4[i];
        int w0 = (int)fminf(fmaxf(truncf(a.x * wscale), -127.f), 127.f);
        int w1 = (int)fminf(fmaxf(truncf(a.y * wscale), -127.f), 127.f);
        int w2 = (int)fminf(fmaxf(truncf(a.z * wscale), -127.f), 127.f);
        int w3 = (int)fminf(fmaxf(truncf(a.w * wscale), -127.f), 127.f);
        wq4[i] = (w0 & 0xff) | ((w1 & 0xff) << 8) | ((w2 & 0xff) << 16) | (w3 << 24);
        float4 b = x4[i];
        int x0 = (int)rintf(b.x * xscale);
        int x1 = (int)rintf(b.y * xscale);
        int x2 = (int)rintf(b.z * xscale);
        int x3 = (int)rintf(b.w * xscale);
        xq4[i] = (x0 & 0xff) | ((x1 & 0xff) << 8) | ((x2 & 0xff) << 16) | (x3 << 24);
    }
}

// ---------------- Kernel 3: 256x256 8-phase i8 GEMM, C = (A*B^T)*dq + bias ----------------
// A: xq [M][K] i8, B: wq [N][K] i8, C fp32. K-tile = 128 i8 = 128B rows: byte-identical
// LDS geometry/swizzle/staging to the verified bf16 kernel. mfma_i32_16x16x64_i8, kk-outer.
// sM layout: A-buf0 [0,32K) A-buf1 [32K,64K) B-buf0 [64K,96K) B-buf1 [96K,128K).
#define BAR()   __builtin_amdgcn_s_barrier()
#define FENCE() __builtin_amdgcn_sched_barrier(0)
#define VM6()   do { asm volatile("s_waitcnt vmcnt(6)"); FENCE(); } while(0)

#define MFMA_I8(ACC, AF, BF) \
    asm("v_mfma_i32_16x16x64_i8 %0, %1, %2, %0" : "+v"(ACC) : "v"(AF), "v"(BF))

__global__ __launch_bounds__(512, 2) void gemm_i8(
    const char* __restrict__ A,
    const char* __restrict__ B,
    const unsigned int* __restrict__ mb,
    const float* __restrict__ bias,
    float* __restrict__ C)
{
    __shared__ __align__(16) char sM[131072];

    int bid = (blockIdx.x & 7) * 32 + (blockIdx.x >> 3);   // XCD-bijective (nwg=256)
    const int bm = bid >> 4;
    const int bn = bid & 15;

    const int t    = threadIdx.x;
    const int wave = t >> 6;
    const int lane = t & 63;
    const int wm   = wave >> 2;     // 0..1
    const int wn   = wave & 3;      // 0..3

    i32x4 acc[2][2][4][2] = {};     // [h][g][mi][ni], i32 exact

    // LDS-read bases: per-thread VGPR + compile-time immediates.
    // row = (16-blk) + (lane&15); byte = row*128 + kk*64 + (lane>>4)*16, then ^=(row&7)<<4.
    // row&7 == lane&7 (all row-block offsets are multiples of 8 rows) -> fold XOR into base;
    // kk toggles only bit 6 -> base^64 variant.
    const int chunk = (((lane >> 4) << 4) ^ ((lane & 7) << 4));
    const int lbA0 = ((lane & 15) << 7) + chunk + wm * 8192;
    const int lbA1 = lbA0 ^ 64;
    const int lbB0 = ((lane & 15) << 7) + chunk + wn * 4096 + 65536;
    const int lbB1 = lbB0 ^ 64;

    // Staging: thread t owns linear LDS slot t*16 (+8192 for 2nd 64-row block);
    // source chunk pre-swizzled so LDS[row][c] = SRC[row][c^(row&7)].
    const int srow = t >> 3;
    const int cch  = (t & 7) ^ (srow & 7);
    const char* Abase = A + (size_t)(bm * 256 + srow) * K_DIM + cch * 16;
    const char* Bbase = B + (size_t)(bn * 256 + srow) * K_DIM + cch * 16;
    const int wave_lds = wave * 1024;

    // REG: 0 = A region, 65536 = B region. Half-tile = 128 rows x 128B = 2 loads/thread.
#define STAGE(SRC, REG, H, KT, BUF) do {                                                \
        const char* _s = SRC + (H) * (128 * K_DIM) + ((KT) << 7);                       \
        char* _d = sM + (REG) + (BUF) * 32768 + (H) * 16384 + wave_lds;                 \
        __builtin_amdgcn_global_load_lds(                                               \
            (const __attribute__((address_space(1))) void*)_s,                          \
            (__attribute__((address_space(3))) void*)_d, 16, 0, 0);                     \
        __builtin_amdgcn_global_load_lds(                                               \
            (const __attribute__((address_space(1))) void*)(_s + (size_t)64 * K_DIM),   \
            (__attribute__((address_space(3))) void*)(_d + 8192), 16, 0, 0);            \
    } while(0)

#define LDA(H, BUF, AF) do {                                                            \
        _Pragma("unroll") for (int mi = 0; mi < 4; ++mi) {                              \
            AF[mi][0] = *(const i32x4*)(sM + (BUF)*32768 + (H)*16384 + mi*2048 + lbA0); \
            AF[mi][1] = *(const i32x4*)(sM + (BUF)*32768 + (H)*16384 + mi*2048 + lbA1); \
        }                                                                               \
    } while(0)

#define LDB(G, BUF, BF) do {                                                            \
        _Pragma("unroll") for (int ni = 0; ni < 2; ++ni) {                              \
            BF[ni][0] = *(const i32x4*)(sM + (BUF)*32768 + (G)*16384 + ni*2048 + lbB0); \
            BF[ni][1] = *(const i32x4*)(sM + (BUF)*32768 + (G)*16384 + ni*2048 + lbB1); \
        }                                                                               \
    } while(0)

    // kk OUTER: 8 independent accs between dependent reuses of the same acc.
#define MMA(H, G, AF, BF) do {                                                          \
        __builtin_amdgcn_s_setprio(1);                                                  \
        _Pragma("unroll") for (int kk = 0; kk < 2; ++kk)                                \
        _Pragma("unroll") for (int mi = 0; mi < 4; ++mi)                                \
        _Pragma("unroll") for (int ni = 0; ni < 2; ++ni)                                \
            MFMA_I8(acc[H][G][mi][ni], AF[mi][kk], BF[ni][kk]);                         \
        __builtin_amdgcn_s_setprio(0);                                                  \
    } while(0)

    // Prologue: tile0 fully + tile1 minus A1 (7 half-tile units = 14 loads);
    // vmcnt(6) -> all of tile0 landed.
    STAGE(Abase, 0,     0, 0, 0);
    STAGE(Abase, 0,     1, 0, 0);
    STAGE(Bbase, 65536, 0, 0, 0);
    STAGE(Bbase, 65536, 1, 0, 0);
    STAGE(Abase, 0,     0, 1, 1);
    STAGE(Bbase, 65536, 0, 1, 1);
    STAGE(Bbase, 65536, 1, 1, 1);
    VM6();
    BAR();

    i32x4 af[4][2], bf0[2][2], bf1[2][2];

    for (int it = 0; it < 16; ++it) {
        // ---- K-tile 2it in buf0: quadrants (0,0) (0,1) (1,1) (1,0) ----
        // P1
        LDA(0, 0, af); LDB(0, 0, bf0);
        STAGE(Abase, 0, 1, (2*it + 1) & 31, 1);
        BAR();
        MMA(0, 0, af, bf0);
        BAR();
        // P2
        LDB(1, 0, bf1);
        STAGE(Abase, 0, 0, (2*it + 2) & 31, 0);
        BAR();
        MMA(0, 1, af, bf1);
        BAR();
        // P3
        LDA(1, 0, af);
        STAGE(Bbase, 65536, 0, (2*it + 2) & 31, 0);
        BAR();
        MMA(1, 1, af, bf1);
        BAR();
        // P4
        STAGE(Bbase, 65536, 1, (2*it + 2) & 31, 0);
        VM6();
        BAR();
        MMA(1, 0, af, bf0);
        BAR();

        // ---- K-tile 2it+1 in buf1 ----
        // P5
        LDA(0, 1, af); LDB(0, 1, bf0);
        STAGE(Abase, 0, 1, (2*it + 2) & 31, 0);
        BAR();
        MMA(0, 0, af, bf0);
        BAR();
        // P6
        LDB(1, 1, bf1);
        STAGE(Abase, 0, 0, (2*it + 3) & 31, 1);
        BAR();
        MMA(0, 1, af, bf1);
        BAR();
        // P7
        LDA(1, 1, af);
        STAGE(Bbase, 65536, 0, (2*it + 3) & 31, 1);
        BAR();
        MMA(1, 1, af, bf1);
        BAR();
        // P8
        STAGE(Bbase, 65536, 1, (2*it + 3) & 31, 1);
        VM6();
        BAR();
        MMA(1, 0, af, bf0);
        BAR();
    }

    asm volatile("s_waitcnt vmcnt(0)");   // drain tail stages before stores/endpgm

    // dequant scale: (wmax/127) * (xmax/127)
    const float dq = (__uint_as_float(mb[0]) * (1.0f / 127.0f)) *
                     (__uint_as_float(mb[1]) * (1.0f / 127.0f));

    // ---- epilogue: D layout (16x16, m89): col = lane&15, row = (lane>>4)*4 + reg ----
    #pragma unroll
    for (int h = 0; h < 2; ++h)
    #pragma unroll
    for (int g = 0; g < 2; ++g)
    #pragma unroll
    for (int mi = 0; mi < 4; ++mi)
    #pragma unroll
    for (int ni = 0; ni < 2; ++ni) {
        const int grow0 = bm * 256 + h * 128 + wm * 64 + mi * 16 + (lane >> 4) * 4;
        const int gcol  = bn * 256 + g * 128 + wn * 32 + ni * 16 + (lane & 15);
        const float bv = bias[gcol];
        #pragma unroll
        for (int rg = 0; rg < 4; ++rg)
            C[(size_t)(grow0 + rg) * N_DIM + gcol] =
                (float)acc[h][g][mi][ni][rg] * dq + bv;
    }

#undef STAGE
#undef LDA
#undef LDB
#undef MMA
}

extern "C" void kernel_launch(void* const* d_in, const int* in_sizes, int n_in,
                              void* d_out, int out_size, void* d_ws, size_t ws_size,
                              hipStream_t stream) {
    const float* x    = (const float*)d_in[0];   // [4096, 4096]
    const float* w    = (const float*)d_in[1];   // [4096, 4096]
    const float* bias = (const float*)d_in[2];   // [4096]
    float* out = (float*)d_out;

    unsigned int* maxbits = (unsigned int*)d_ws;                       // [0]=wmax,[1]=xmax
    char* xq = (char*)d_ws + 256;
    char* wq = (char*)d_ws + 256 + (size_t)M_DIM * K_DIM;

    hipMemsetAsync(d_ws, 0, 8, stream);

    const int n4 = (N_DIM * K_DIM) / 4;
    maxabs2_kernel<<<1024, 256, 0, stream>>>(w, x, maxbits, n4);
    quant_kernel<<<2048, 256, 0, stream>>>(w, x, maxbits, (int*)wq, (int*)xq, n4);

    const int grid = (M_DIM / 256) * (N_DIM / 256);  // 256
    gemm_i8<<<grid, 512, 0, stream>>>(xq, wq, maxbits, bias, out);
}

// Round 5
// 119.772 us; speedup vs baseline: 2.7358x; 1.1261x over previous
//
#include <hip/hip_runtime.h>
#include <stdint.h>

#define M_DIM 4096
#define N_DIM 4096
#define K_DIM 4096

typedef int i32x4 __attribute__((ext_vector_type(4)));

// ---- Kernel 1: wmax = max|W| -> uint bits (one atomic per block) ----
__global__ void maxabs_kernel(const float* __restrict__ w,
                              unsigned int* __restrict__ out_bits, int n4) {
    __shared__ float sred[4];
    int tid = blockIdx.x * blockDim.x + threadIdx.x;
    int stride = gridDim.x * blockDim.x;
    const float4* w4 = (const float4*)w;
    float m = 0.f;
    for (int i = tid; i < n4; i += stride) {
        float4 a = w4[i];
        m = fmaxf(m, fmaxf(fmaxf(fabsf(a.x), fabsf(a.y)), fmaxf(fabsf(a.z), fabsf(a.w))));
    }
    for (int off = 32; off > 0; off >>= 1) m = fmaxf(m, __shfl_xor(m, off));
    if ((threadIdx.x & 63) == 0) sred[threadIdx.x >> 6] = m;
    __syncthreads();
    if (threadIdx.x == 0) {
        m = fmaxf(fmaxf(sred[0], sred[1]), fmaxf(sred[2], sred[3]));
        atomicMax(out_bits, __float_as_uint(m));   // |w|>=0: uint order == float order
    }
}

// ---- Kernel 2: W -> int8 (trunc, exact reference grid) ----
__global__ void wquant_kernel(const float* __restrict__ w,
                              const unsigned int* __restrict__ mb,
                              int* __restrict__ wq4, int n4) {
    const float wscale = 127.0f / __uint_as_float(mb[0]);
    int tid = blockIdx.x * blockDim.x + threadIdx.x;
    int stride = gridDim.x * blockDim.x;
    const float4* w4 = (const float4*)w;
    for (int i = tid; i < n4; i += stride) {
        float4 a = w4[i];
        int w0 = (int)fminf(fmaxf(truncf(a.x * wscale), -127.f), 127.f);
        int w1 = (int)fminf(fmaxf(truncf(a.y * wscale), -127.f), 127.f);
        int w2 = (int)fminf(fmaxf(truncf(a.z * wscale), -127.f), 127.f);
        int w3 = (int)fminf(fmaxf(truncf(a.w * wscale), -127.f), 127.f);
        wq4[i] = (w0 & 0xff) | ((w1 & 0xff) << 8) | ((w2 & 0xff) << 16) | (w3 << 24);
    }
}

// ---- Kernel 3: x -> int8 with PER-ROW scale, single pass; xsinv[row] = rowmax/127 ----
__global__ void xrowquant_kernel(const float* __restrict__ x,
                                 char* __restrict__ xq,
                                 float* __restrict__ xsinv) {
    __shared__ float sred[4];
    const int row = blockIdx.x;
    const int t = threadIdx.x;
    const float4* xr = (const float4*)(x + (size_t)row * K_DIM);
    float4 v[4];
    float m = 0.f;
    #pragma unroll
    for (int i = 0; i < 4; ++i) {
        v[i] = xr[t * 4 + i];
        m = fmaxf(m, fmaxf(fmaxf(fabsf(v[i].x), fabsf(v[i].y)),
                           fmaxf(fabsf(v[i].z), fabsf(v[i].w))));
    }
    for (int off = 32; off > 0; off >>= 1) m = fmaxf(m, __shfl_xor(m, off));
    if ((t & 63) == 0) sred[t >> 6] = m;
    __syncthreads();
    m = fmaxf(fmaxf(fmaxf(sred[0], sred[1]), fmaxf(sred[2], sred[3])), 1e-30f);
    if (t == 0) xsinv[row] = m * (1.0f / 127.0f);
    const float scale = 127.0f / m;
    int4 o;
    int* op = (int*)&o;
    #pragma unroll
    for (int i = 0; i < 4; ++i) {
        int a = (int)rintf(v[i].x * scale);
        int b = (int)rintf(v[i].y * scale);
        int c = (int)rintf(v[i].z * scale);
        int d = (int)rintf(v[i].w * scale);
        op[i] = (a & 0xff) | ((b & 0xff) << 8) | ((c & 0xff) << 16) | (d << 24);
    }
    *(int4*)(xq + (size_t)row * K_DIM + t * 16) = o;
}

// ------------- Kernel 4: 256x256 i8 GEMM, 2 phases/K-tile, C = acc*rowscale + bias -------------
// A: xq [M][K] i8, B: wq [N][K] i8. K-tile = 128B rows. LDS 128KB: A buf0/buf1 at 0/32K,
// B buf0/buf1 at 64K/96K. Swizzle byte ^= (row&7)<<4 both-sides. mfma_i32_16x16x64_i8 kk-outer.
// Phase = [ds_reads; 2xSTAGE; vmcnt(N); BAR; 32 MFMA; BAR]. vmcnt(8) end-Ph1, vmcnt(4) end-Ph2:
// per-wave counted wait + barrier => all waves' older stages landed before dependent ds_reads.
#define BAR()   __builtin_amdgcn_s_barrier()
#define FENCE() __builtin_amdgcn_sched_barrier(0)
#define VM8()   do { asm volatile("s_waitcnt vmcnt(8)"); FENCE(); } while(0)
#define VM4()   do { asm volatile("s_waitcnt vmcnt(4)"); FENCE(); } while(0)

#define MFMA_I8(ACC, AF, BF) \
    asm("v_mfma_i32_16x16x64_i8 %0, %1, %2, %0" : "+v"(ACC) : "v"(AF), "v"(BF))

__global__ __launch_bounds__(512, 2) void gemm_i8(
    const char* __restrict__ A,
    const char* __restrict__ B,
    const unsigned int* __restrict__ mb,
    const float* __restrict__ xsinv,
    const float* __restrict__ bias,
    float* __restrict__ C)
{
    __shared__ __align__(16) char sM[131072];

    int bid = (blockIdx.x & 7) * 32 + (blockIdx.x >> 3);   // XCD-bijective (nwg=256)
    const int bm = bid >> 4;
    const int bn = bid & 15;

    const int t    = threadIdx.x;
    const int wave = t >> 6;
    const int lane = t & 63;
    const int wm   = wave >> 2;     // 0..1
    const int wn   = wave & 3;      // 0..3

    i32x4 acc[2][2][4][2] = {};     // [h][g][mi][ni]

    // LDS-read bases (fold swizzle: row&7 == lane&7 for all our row-blocks)
    const int chunk = (((lane >> 4) << 4) ^ ((lane & 7) << 4));
    const int lbA0 = ((lane & 15) << 7) + chunk + wm * 8192;
    const int lbA1 = lbA0 ^ 64;
    const int lbB0 = ((lane & 15) << 7) + chunk + wn * 4096 + 65536;
    const int lbB1 = lbB0 ^ 64;

    // Staging: thread t owns linear LDS slot t*16 (+8192 for 2nd 64-row block);
    // source chunk pre-swizzled so LDS[row][c] = SRC[row][c^(row&7)].
    const int srow = t >> 3;
    const int cch  = (t & 7) ^ (srow & 7);
    const char* Abase = A + (size_t)(bm * 256 + srow) * K_DIM + cch * 16;
    const char* Bbase = B + (size_t)(bn * 256 + srow) * K_DIM + cch * 16;
    const int wave_lds = wave * 1024;

#define STAGE(SRC, REG, H, KT, BUF) do {                                                \
        const char* _s = SRC + (H) * (128 * K_DIM) + ((KT) << 7);                       \
        char* _d = sM + (REG) + (BUF) * 32768 + (H) * 16384 + wave_lds;                 \
        __builtin_amdgcn_global_load_lds(                                               \
            (const __attribute__((address_space(1))) void*)_s,                          \
            (__attribute__((address_space(3))) void*)_d, 16, 0, 0);                     \
        __builtin_amdgcn_global_load_lds(                                               \
            (const __attribute__((address_space(1))) void*)(_s + (size_t)64 * K_DIM),   \
            (__attribute__((address_space(3))) void*)(_d + 8192), 16, 0, 0);            \
    } while(0)

#define LDA(H, BUF) do {                                                                \
        _Pragma("unroll") for (int mi = 0; mi < 4; ++mi) {                              \
            af[mi][0] = *(const i32x4*)(sM + (BUF)*32768 + (H)*16384 + mi*2048 + lbA0); \
            af[mi][1] = *(const i32x4*)(sM + (BUF)*32768 + (H)*16384 + mi*2048 + lbA1); \
        }                                                                               \
    } while(0)

#define LDB(G, BUF, BF) do {                                                            \
        _Pragma("unroll") for (int ni = 0; ni < 2; ++ni) {                              \
            BF[ni][0] = *(const i32x4*)(sM + (BUF)*32768 + (G)*16384 + ni*2048 + lbB0); \
            BF[ni][1] = *(const i32x4*)(sM + (BUF)*32768 + (G)*16384 + ni*2048 + lbB1); \
        }                                                                               \
    } while(0)

    // 32 MFMA for row-half H x both col-halves, kk-outer (16 indep accs between reuse)
#define MMA2(H) do {                                                                    \
        __builtin_amdgcn_s_setprio(1);                                                  \
        _Pragma("unroll") for (int kk = 0; kk < 2; ++kk)                                \
        _Pragma("unroll") for (int mi = 0; mi < 4; ++mi)                                \
        _Pragma("unroll") for (int ni = 0; ni < 2; ++ni) {                              \
            MFMA_I8(acc[H][0][mi][ni], af[mi][kk], bf0[ni][kk]);                        \
            MFMA_I8(acc[H][1][mi][ni], af[mi][kk], bf1[ni][kk]);                        \
        }                                                                               \
        __builtin_amdgcn_s_setprio(0);                                                  \
    } while(0)

    // Prologue: A0(0),B0(0),B1(0),A1(0),A0(1),B0(1) = 12 loads; allow newest 4 in flight.
    STAGE(Abase, 0,     0, 0, 0);
    STAGE(Bbase, 65536, 0, 0, 0);
    STAGE(Bbase, 65536, 1, 0, 0);
    STAGE(Abase, 0,     1, 0, 0);
    STAGE(Abase, 0,     0, 1, 1);
    STAGE(Bbase, 65536, 0, 1, 1);
    VM4();
    BAR();

    i32x4 af[4][2], bf0[2][2], bf1[2][2];

    for (int it = 0; it < 16; ++it) {
        // ======== tile T = 2it (buf0) ========
        // Ph1: reads A0,B0,B1(T); stages B1(T+1),A1(T+1) -> buf1
        LDA(0, 0); LDB(0, 0, bf0); LDB(1, 0, bf1);
        STAGE(Bbase, 65536, 1, (2*it + 1) & 31, 1);
        STAGE(Abase, 0,     1, (2*it + 1) & 31, 1);
        VM8();
        BAR();
        MMA2(0);
        BAR();
        // Ph2: reads A1(T); stages A0(T+2),B0(T+2) -> buf0
        LDA(1, 0);
        STAGE(Abase, 0,     0, (2*it + 2) & 31, 0);
        STAGE(Bbase, 65536, 0, (2*it + 2) & 31, 0);
        VM4();
        BAR();
        MMA2(1);
        BAR();

        // ======== tile T+1 (buf1) ========
        // Ph1: stages B1(T+2),A1(T+2) -> buf0
        LDA(0, 1); LDB(0, 1, bf0); LDB(1, 1, bf1);
        STAGE(Bbase, 65536, 1, (2*it + 2) & 31, 0);
        STAGE(Abase, 0,     1, (2*it + 2) & 31, 0);
        VM8();
        BAR();
        MMA2(0);
        BAR();
        // Ph2: stages A0(T+3),B0(T+3) -> buf1
        LDA(1, 1);
        STAGE(Abase, 0,     0, (2*it + 3) & 31, 1);
        STAGE(Bbase, 65536, 0, (2*it + 3) & 31, 1);
        VM4();
        BAR();
        MMA2(1);
        BAR();
    }

    asm volatile("s_waitcnt vmcnt(0)");   // drain tail stages

    const float wdq = __uint_as_float(mb[0]) * (1.0f / 127.0f);

    // Epilogue: D layout (m89): col = lane&15, row = (lane>>4)*4 + reg.
    // C = acc * (wdq * xsinv[row]) + bias[col]
    #pragma unroll
    for (int h = 0; h < 2; ++h)
    #pragma unroll
    for (int mi = 0; mi < 4; ++mi) {
        const int grow0 = bm * 256 + h * 128 + wm * 64 + mi * 16 + (lane >> 4) * 4;
        float rs[4];
        #pragma unroll
        for (int rg = 0; rg < 4; ++rg) rs[rg] = xsinv[grow0 + rg] * wdq;
        #pragma unroll
        for (int g = 0; g < 2; ++g)
        #pragma unroll
        for (int ni = 0; ni < 2; ++ni) {
            const int gcol = bn * 256 + g * 128 + wn * 32 + ni * 16 + (lane & 15);
            const float bv = bias[gcol];
            #pragma unroll
            for (int rg = 0; rg < 4; ++rg)
                C[(size_t)(grow0 + rg) * N_DIM + gcol] =
                    (float)acc[h][g][mi][ni][rg] * rs[rg] + bv;
        }
    }

#undef STAGE
#undef LDA
#undef LDB
#undef MMA2
}

extern "C" void kernel_launch(void* const* d_in, const int* in_sizes, int n_in,
                              void* d_out, int out_size, void* d_ws, size_t ws_size,
                              hipStream_t stream) {
    const float* x    = (const float*)d_in[0];   // [4096, 4096]
    const float* w    = (const float*)d_in[1];   // [4096, 4096]
    const float* bias = (const float*)d_in[2];   // [4096]
    float* out = (float*)d_out;

    unsigned int* maxbits = (unsigned int*)d_ws;            // [0]=wmax bits
    float* xsinv = (float*)((char*)d_ws + 256);             // [4096]
    char*  xq    = (char*)d_ws + 32768;                     // 16 MB
    char*  wq    = (char*)d_ws + 32768 + (size_t)M_DIM * K_DIM;

    hipMemsetAsync(d_ws, 0, 8, stream);

    const int n4 = (N_DIM * K_DIM) / 4;
    maxabs_kernel<<<1024, 256, 0, stream>>>(w, maxbits, n4);
    wquant_kernel<<<2048, 256, 0, stream>>>(w, maxbits, (int*)wq, n4);
    xrowquant_kernel<<<M_DIM, 256, 0, stream>>>(x, xq, xsinv);

    const int grid = (M_DIM / 256) * (N_DIM / 256);  // 256
    gemm_i8<<<grid, 512, 0, stream>>>(xq, wq, maxbits, xsinv, bias, out);
}

// Round 6
// 114.438 us; speedup vs baseline: 2.8633x; 1.0466x over previous
//
#include <hip/hip_runtime.h>
#include <stdint.h>

#define M_DIM 4096
#define N_DIM 4096
#define K_DIM 4096

typedef int i32x4 __attribute__((ext_vector_type(4)));

// ---- Kernel 1: wmax = max|W| -> uint bits (one atomic per block) ----
__global__ void maxabs_kernel(const float* __restrict__ w,
                              unsigned int* __restrict__ out_bits, int n4) {
    __shared__ float sred[4];
    int tid = blockIdx.x * blockDim.x + threadIdx.x;
    int stride = gridDim.x * blockDim.x;
    const float4* w4 = (const float4*)w;
    float m = 0.f;
    for (int i = tid; i < n4; i += stride) {
        float4 a = w4[i];
        m = fmaxf(m, fmaxf(fmaxf(fabsf(a.x), fabsf(a.y)), fmaxf(fabsf(a.z), fabsf(a.w))));
    }
    for (int off = 32; off > 0; off >>= 1) m = fmaxf(m, __shfl_xor(m, off));
    if ((threadIdx.x & 63) == 0) sred[threadIdx.x >> 6] = m;
    __syncthreads();
    if (threadIdx.x == 0) {
        m = fmaxf(fmaxf(sred[0], sred[1]), fmaxf(sred[2], sred[3]));
        atomicMax(out_bits, __float_as_uint(m));   // |w|>=0: uint order == float order
    }
}

// ---- Kernel 2 (fused): blocks 0..4095: x-row quant; blocks 4096..6143: W quant ----
__global__ void quantfuse_kernel(const float* __restrict__ w,
                                 const float* __restrict__ x,
                                 const unsigned int* __restrict__ mb,
                                 int* __restrict__ wq4,
                                 char* __restrict__ xq,
                                 float* __restrict__ xsinv, int n4) {
    __shared__ float sred[4];
    if (blockIdx.x < 4096) {
        // ---- x -> int8, per-row scale; xsinv[row] = rowmax/127 ----
        const int row = blockIdx.x;
        const int t = threadIdx.x;
        const float4* xr = (const float4*)(x + (size_t)row * K_DIM);
        float4 v[4];
        float m = 0.f;
        #pragma unroll
        for (int i = 0; i < 4; ++i) {
            v[i] = xr[t * 4 + i];
            m = fmaxf(m, fmaxf(fmaxf(fabsf(v[i].x), fabsf(v[i].y)),
                               fmaxf(fabsf(v[i].z), fabsf(v[i].w))));
        }
        for (int off = 32; off > 0; off >>= 1) m = fmaxf(m, __shfl_xor(m, off));
        if ((t & 63) == 0) sred[t >> 6] = m;
        __syncthreads();
        m = fmaxf(fmaxf(fmaxf(sred[0], sred[1]), fmaxf(sred[2], sred[3])), 1e-30f);
        if (t == 0) xsinv[row] = m * (1.0f / 127.0f);
        const float scale = 127.0f / m;
        int4 o;
        int* op = (int*)&o;
        #pragma unroll
        for (int i = 0; i < 4; ++i) {
            int a = (int)rintf(v[i].x * scale);
            int b = (int)rintf(v[i].y * scale);
            int c = (int)rintf(v[i].z * scale);
            int d = (int)rintf(v[i].w * scale);
            op[i] = (a & 0xff) | ((b & 0xff) << 8) | ((c & 0xff) << 16) | (d << 24);
        }
        *(int4*)(xq + (size_t)row * K_DIM + t * 16) = o;
    } else {
        // ---- W -> int8 (trunc, exact reference grid) ----
        const float wscale = 127.0f / __uint_as_float(mb[0]);
        int tid = (blockIdx.x - 4096) * blockDim.x + threadIdx.x;
        const int stride = 2048 * 256;
        const float4* w4 = (const float4*)w;
        for (int i = tid; i < n4; i += stride) {
            float4 a = w4[i];
            int w0 = (int)fminf(fmaxf(truncf(a.x * wscale), -127.f), 127.f);
            int w1 = (int)fminf(fmaxf(truncf(a.y * wscale), -127.f), 127.f);
            int w2 = (int)fminf(fmaxf(truncf(a.z * wscale), -127.f), 127.f);
            int w3 = (int)fminf(fmaxf(truncf(a.w * wscale), -127.f), 127.f);
            wq4[i] = (w0 & 0xff) | ((w1 & 0xff) << 8) | ((w2 & 0xff) << 16) | (w3 << 24);
        }
    }
}

// ------------- Kernel 3: 256x256 i8 GEMM, 1 barrier/K-tile, within-wave pipe overlap -------------
// A: xq [M][K] i8, B: wq [N][K] i8. K-tile = 128B rows. LDS 128KB: A buf0/1 at 0/32K, B at 64K/96K.
// Swizzle byte ^= (row&7)<<4 both-sides. All 24 ds_reads + 4 STAGEs issued upfront (order pinned);
// 64 MFMA in one region -> compiler emits counted lgkmcnt(12/8/0) so LDS pipe drains under MFMA.
// Cross-wave sync: vmcnt(0)+s_barrier once per K-tile (stage visibility + buf-swap WAR).
#define BAR()   __builtin_amdgcn_s_barrier()
#define FENCE() __builtin_amdgcn_sched_barrier(0)

#define MFMA_I8(ACC, AF, BF) \
    asm("v_mfma_i32_16x16x64_i8 %0, %1, %2, %0" : "+v"(ACC) : "v"(AF), "v"(BF))

__global__ __launch_bounds__(512, 2) void gemm_i8(
    const char* __restrict__ A,
    const char* __restrict__ B,
    const unsigned int* __restrict__ mb,
    const float* __restrict__ xsinv,
    const float* __restrict__ bias,
    float* __restrict__ C)
{
    __shared__ __align__(16) char sM[131072];

    int bid = (blockIdx.x & 7) * 32 + (blockIdx.x >> 3);   // XCD-bijective (nwg=256)
    const int bm = bid >> 4;
    const int bn = bid & 15;

    const int t    = threadIdx.x;
    const int wave = t >> 6;
    const int lane = t & 63;
    const int wm   = wave >> 2;     // 0..1
    const int wn   = wave & 3;      // 0..3

    i32x4 acc[2][2][4][2] = {};     // [h][g][mi][ni]

    // LDS-read bases (swizzle folded: row&7 == lane&7 for all row-blocks used)
    const int chunk = (((lane >> 4) << 4) ^ ((lane & 7) << 4));
    const int lbA0 = ((lane & 15) << 7) + chunk + wm * 8192;
    const int lbA1 = lbA0 ^ 64;
    const int lbB0 = ((lane & 15) << 7) + chunk + wn * 4096 + 65536;
    const int lbB1 = lbB0 ^ 64;

    // Staging: thread t owns linear LDS slot t*16 (+8192 for 2nd 64-row block);
    // source chunk pre-swizzled so LDS[row][c] = SRC[row][c^(row&7)].
    const int srow = t >> 3;
    const int cch  = (t & 7) ^ (srow & 7);
    const char* Abase = A + (size_t)(bm * 256 + srow) * K_DIM + cch * 16;
    const char* Bbase = B + (size_t)(bn * 256 + srow) * K_DIM + cch * 16;
    const int wave_lds = wave * 1024;

#define STAGE(SRC, REG, H, KT, BUF) do {                                                \
        const char* _s = SRC + (H) * (128 * K_DIM) + ((KT) << 7);                       \
        char* _d = sM + (REG) + (BUF) * 32768 + (H) * 16384 + wave_lds;                 \
        __builtin_amdgcn_global_load_lds(                                               \
            (const __attribute__((address_space(1))) void*)_s,                          \
            (__attribute__((address_space(3))) void*)_d, 16, 0, 0);                     \
        __builtin_amdgcn_global_load_lds(                                               \
            (const __attribute__((address_space(1))) void*)(_s + (size_t)64 * K_DIM),   \
            (__attribute__((address_space(3))) void*)(_d + 8192), 16, 0, 0);            \
    } while(0)

#define LDA(H, BUF, AF) do {                                                            \
        _Pragma("unroll") for (int mi = 0; mi < 4; ++mi) {                              \
            AF[mi][0] = *(const i32x4*)(sM + (BUF)*32768 + (H)*16384 + mi*2048 + lbA0); \
            AF[mi][1] = *(const i32x4*)(sM + (BUF)*32768 + (H)*16384 + mi*2048 + lbA1); \
        }                                                                               \
    } while(0)

#define LDB(G, BUF, BF) do {                                                            \
        _Pragma("unroll") for (int ni = 0; ni < 2; ++ni) {                              \
            BF[ni][0] = *(const i32x4*)(sM + (BUF)*32768 + (G)*16384 + ni*2048 + lbB0); \
            BF[ni][1] = *(const i32x4*)(sM + (BUF)*32768 + (G)*16384 + ni*2048 + lbB1); \
        }                                                                               \
    } while(0)

    // one C-quadrant x K=128: 16 MFMA, kk-outer (8 indep accs between acc reuse)
#define MMAQ(H, G, AF, BF)                                                              \
        _Pragma("unroll") for (int kk = 0; kk < 2; ++kk)                                \
        _Pragma("unroll") for (int mi = 0; mi < 4; ++mi)                                \
        _Pragma("unroll") for (int ni = 0; ni < 2; ++ni)                                \
            MFMA_I8(acc[H][G][mi][ni], AF[mi][kk], BF[ni][kk]);

    // One K-tile: reads from BUF, stages K-tile KN into OBUF, 64 MFMA, 1 barrier.
#define TILE(BUF, OBUF, KN) do {                                                        \
        LDA(0, BUF, af0); LDB(0, BUF, bf0);      /* 12 reads for Q(0,0) */              \
        FENCE();                                                                        \
        LDB(1, BUF, bf1);                        /* 4 reads */                          \
        STAGE(Abase, 0,     0, KN, OBUF);                                               \
        STAGE(Bbase, 65536, 0, KN, OBUF);                                               \
        STAGE(Abase, 0,     1, KN, OBUF);                                               \
        STAGE(Bbase, 65536, 1, KN, OBUF);                                               \
        LDA(1, BUF, af1);                        /* 8 reads */                          \
        FENCE();                                                                        \
        __builtin_amdgcn_s_setprio(1);                                                  \
        MMAQ(0, 0, af0, bf0);                                                           \
        MMAQ(0, 1, af0, bf1);                                                           \
        MMAQ(1, 1, af1, bf1);                                                           \
        MMAQ(1, 0, af1, bf0);                                                           \
        __builtin_amdgcn_s_setprio(0);                                                  \
        asm volatile("s_waitcnt vmcnt(0)");      /* stages (issued ~2600cy ago) landed */\
        BAR();                                                                          \
        FENCE();                                                                        \
    } while(0)

    // Prologue: stage tile 0 -> buf0 only.
    STAGE(Abase, 0,     0, 0, 0);
    STAGE(Bbase, 65536, 0, 0, 0);
    STAGE(Abase, 0,     1, 0, 0);
    STAGE(Bbase, 65536, 1, 0, 0);
    asm volatile("s_waitcnt vmcnt(0)");
    BAR();
    FENCE();

    i32x4 af0[4][2], af1[4][2], bf0[2][2], bf1[2][2];

    for (int it = 0; it < 16; ++it) {
        TILE(0, 1, (2 * it + 1) & 31);
        TILE(1, 0, (2 * it + 2) & 31);
    }

    const float wdq = __uint_as_float(mb[0]) * (1.0f / 127.0f);

    // Epilogue: D layout (m89): col = lane&15, row = (lane>>4)*4 + reg.
    // C = acc * (wdq * xsinv[row]) + bias[col]
    #pragma unroll
    for (int h = 0; h < 2; ++h)
    #pragma unroll
    for (int mi = 0; mi < 4; ++mi) {
        const int grow0 = bm * 256 + h * 128 + wm * 64 + mi * 16 + (lane >> 4) * 4;
        float rs[4];
        #pragma unroll
        for (int rg = 0; rg < 4; ++rg) rs[rg] = xsinv[grow0 + rg] * wdq;
        #pragma unroll
        for (int g = 0; g < 2; ++g)
        #pragma unroll
        for (int ni = 0; ni < 2; ++ni) {
            const int gcol = bn * 256 + g * 128 + wn * 32 + ni * 16 + (lane & 15);
            const float bv = bias[gcol];
            #pragma unroll
            for (int rg = 0; rg < 4; ++rg)
                C[(size_t)(grow0 + rg) * N_DIM + gcol] =
                    (float)acc[h][g][mi][ni][rg] * rs[rg] + bv;
        }
    }

#undef STAGE
#undef LDA
#undef LDB
#undef MMAQ
#undef TILE
}

extern "C" void kernel_launch(void* const* d_in, const int* in_sizes, int n_in,
                              void* d_out, int out_size, void* d_ws, size_t ws_size,
                              hipStream_t stream) {
    const float* x    = (const float*)d_in[0];   // [4096, 4096]
    const float* w    = (const float*)d_in[1];   // [4096, 4096]
    const float* bias = (const float*)d_in[2];   // [4096]
    float* out = (float*)d_out;

    unsigned int* maxbits = (unsigned int*)d_ws;            // [0]=wmax bits
    float* xsinv = (float*)((char*)d_ws + 256);             // [4096]
    char*  xq    = (char*)d_ws + 32768;                     // 16 MB
    char*  wq    = (char*)d_ws + 32768 + (size_t)M_DIM * K_DIM;

    hipMemsetAsync(d_ws, 0, 8, stream);

    const int n4 = (N_DIM * K_DIM) / 4;
    maxabs_kernel<<<1024, 256, 0, stream>>>(w, maxbits, n4);
    quantfuse_kernel<<<4096 + 2048, 256, 0, stream>>>(w, x, maxbits, (int*)wq, xq, xsinv, n4);

    const int grid = (M_DIM / 256) * (N_DIM / 256);  // 256
    gemm_i8<<<grid, 512, 0, stream>>>(xq, wq, maxbits, xsinv, bias, out);
}